// Round 1
// baseline (17.450 us; speedup 1.0000x reference)
//
#include <hip/hip_runtime.h>
#include <math.h>

#define NA 96
#define NN 95
#define F_RCR 5.2f
#define F_RCA 3.5f
#define F_PI 3.14159265358979323846f

// per-atom output layout: [0..63] radial (species*16 + shfR),
// [64..383] angular (qpair*32 + shfA*8 + shfZ)

__global__ __launch_bounds__(128) void aev_kernel(const int* __restrict__ species,
                                                  const float* __restrict__ coords,
                                                  float* __restrict__ out) {
    const int blk = blockIdx.x;
    const int c = blk / NA;
    const int a = blk % NA;
    const int tid = threadIdx.x;

    __shared__ float sx[NA], sy[NA], sz[NA];
    __shared__ int ssp[NA];
    // compacted angular neighbor list (d <= RCA)
    __shared__ float cfx[NN], cfy[NN], cfz[NN], cfd[NN], cfc[NN];
    __shared__ int cfs[NN];
    __shared__ int Mcnt;
    __shared__ float rad[64];
    __shared__ float ang[320];

    for (int i = tid; i < NA; i += 128) {
        sx[i] = coords[(c * NA + i) * 3 + 0];
        sy[i] = coords[(c * NA + i) * 3 + 1];
        sz[i] = coords[(c * NA + i) * 3 + 2];
        ssp[i] = species[c * NA + i];
    }
    for (int i = tid; i < 64; i += 128) rad[i] = 0.0f;
    for (int i = tid; i < 320; i += 128) ang[i] = 0.0f;
    if (tid == 0) Mcnt = 0;
    __syncthreads();

    const float axp = sx[a], ayp = sy[a], azp = sz[a];

    // neighbors: radial accumulation + angular compaction
    for (int n = tid; n < NN; n += 128) {
        const int j = (a + 1 + n) % NA;
        const float vx = axp - sx[j];
        const float vy = ayp - sy[j];
        const float vz = azp - sz[j];
        const float d = sqrtf(vx * vx + vy * vy + vz * vz);
        const int sp = ssp[j];
        if (d <= F_RCR) {
            const float fc = 0.5f * cosf(F_PI * d / F_RCR) + 0.5f;
            float* radbase = &rad[sp * 16];
#pragma unroll
            for (int k = 0; k < 16; ++k) {
                const float sh = 0.9f + 0.26875f * (float)k;  // linspace(0.9,5.2,17)[:-1]
                const float dd = d - sh;
                const float term = 0.25f * expf(-16.0f * dd * dd) * fc;
                atomicAdd(&radbase[k], term);
            }
        }
        if (d <= F_RCA) {
            const int idx = atomicAdd(&Mcnt, 1);
            cfx[idx] = vx;
            cfy[idx] = vy;
            cfz[idx] = vz;
            cfd[idx] = d;
            cfc[idx] = 0.5f * cosf(F_PI * d / F_RCA) + 0.5f;
            cfs[idx] = sp;
        }
    }
    __syncthreads();

    const int M = Mcnt;
    const int npairs = (M * (M - 1)) >> 1;

    // cos/sin of ShfZ[t] = (t+0.5)*pi/8
    const float cZ[8] = {0.98078528f, 0.83146961f, 0.55557023f, 0.19509032f,
                         -0.19509032f, -0.55557023f, -0.83146961f, -0.98078528f};
    const float sZ[8] = {0.19509032f, 0.55557023f, 0.83146961f, 0.98078528f,
                         0.98078528f, 0.83146961f, 0.55557023f, 0.19509032f};

    for (int p = tid; p < npairs; p += 128) {
        // decode upper-triangular pair index p -> (i, j), i < j < M
        // rowStart(i) = i*(2M - i - 1)/2
        int i = (int)((float)(2 * M - 1) * 0.5f -
                      0.5f * sqrtf((float)((2 * M - 1) * (2 * M - 1)) - 8.0f * (float)p));
        if (i < 0) i = 0;
        if (i > M - 2) i = M - 2;
        while (i > 0 && p < (i * (2 * M - i - 1)) / 2) --i;
        while (p >= ((i + 1) * (2 * M - i - 2)) / 2) ++i;
        const int j = i + 1 + (p - (i * (2 * M - i - 1)) / 2);

        const float d1 = cfd[i], d2 = cfd[j];
        const float dot = cfx[i] * cfx[j] + cfy[i] * cfy[j] + cfz[i] * cfz[j];
        const float cosang = 0.95f * dot / (d1 * d2);
        const float sinang = sqrtf(1.0f - cosang * cosang);  // |cosang| <= 0.95
        const float fcj = cfc[i] * cfc[j];
        const float dm = 0.5f * (d1 + d2);

        float f2[4];
#pragma unroll
        for (int k = 0; k < 4; ++k) {
            const float sh = 0.9f + 0.65f * (float)k;  // linspace(0.9,3.5,5)[:-1]
            const float dd = dm - sh;
            f2[k] = expf(-8.0f * dd * dd);
        }

        int s1 = cfs[i], s2 = cfs[j];
        if (s1 > s2) { const int t = s1; s1 = s2; s2 = t; }
        const int q = s1 * 4 - (s1 * (s1 - 1)) / 2 + (s2 - s1);  // comb_with_repl index
        float* angbase = &ang[q * 32];

#pragma unroll
        for (int t = 0; t < 8; ++t) {
            // cos(arccos(cosang) - ShfZ[t]) = cosang*cZ + sinang*sZ
            const float b = 0.5f * (1.0f + cosang * cZ[t] + sinang * sZ[t]);
            const float b2 = b * b;
            const float b4 = b2 * b2;
            const float b8 = b4 * b4;
            const float b16 = b8 * b8;
            const float b32 = b16 * b16;  // (.)^Zeta, Zeta=32
            const float pre = 2.0f * b32 * fcj;
#pragma unroll
            for (int k = 0; k < 4; ++k) {
                atomicAdd(&angbase[k * 8 + t], pre * f2[k]);
            }
        }
    }
    __syncthreads();

    float* orow = out + (size_t)(c * NA + a) * 384;
    for (int i = tid; i < 64; i += 128) orow[i] = rad[i];
    for (int i = tid; i < 320; i += 128) orow[64 + i] = ang[i];
}

extern "C" void kernel_launch(void* const* d_in, const int* in_sizes, int n_in,
                              void* d_out, int out_size, void* d_ws, size_t ws_size,
                              hipStream_t stream) {
    const int* species = (const int*)d_in[0];
    const float* coords = (const float*)d_in[1];
    float* out = (float*)d_out;
    const int CA = in_sizes[0];  // C * 96
    aev_kernel<<<CA, 128, 0, stream>>>(species, coords, out);
}

// Round 3
// 17.051 us; speedup vs baseline: 1.0234x; 1.0234x over previous
//
#include <hip/hip_runtime.h>
#include <math.h>

#define NA 96
#define NN 95
#define F_RCR 5.2f
#define F_RCA 3.5f
#define F_PI 3.14159265358979323846f

// per-atom output layout: [0..63] radial (species*16 + shfR),
// [64..383] angular (qpair*32 + shfA*8 + shfZ)

__global__ __launch_bounds__(128) void aev_kernel(const int* __restrict__ species,
                                                  const float* __restrict__ coords,
                                                  float* __restrict__ out) {
    const int blk = blockIdx.x;
    const int c = blk / NA;
    const int a = blk % NA;
    const int tid = threadIdx.x;

    __shared__ float scoord[NA * 3];  // packed xyz
    __shared__ int ssp[NA];
    // compacted angular neighbor list (d <= RCA)
    __shared__ float cfx[NN], cfy[NN], cfz[NN], cfd[NN], cfc[NN];
    __shared__ int cfs[NN];
    __shared__ int Mcnt;
    __shared__ float rad[64];
    __shared__ float ang[320];

    // coords for this conformer: 288 floats = 72 float4 (base is 16B-aligned:
    // c*1152 bytes). Stage vectorized.
    {
        const float4* src = (const float4*)(coords + (size_t)c * NA * 3);
        float4* dst = (float4*)scoord;
        if (tid < 72) dst[tid] = src[tid];
    }
    for (int i = tid; i < NA; i += 128) ssp[i] = species[c * NA + i];
    for (int i = tid; i < 64; i += 128) rad[i] = 0.0f;
    for (int i = tid; i < 320; i += 128) ang[i] = 0.0f;
    if (tid == 0) Mcnt = 0;
    __syncthreads();

    const float axp = scoord[a * 3 + 0], ayp = scoord[a * 3 + 1], azp = scoord[a * 3 + 2];

    // neighbors: radial accumulation + angular compaction
    for (int n = tid; n < NN; n += 128) {
        int j = a + 1 + n;
        if (j >= NA) j -= NA;
        const float vx = axp - scoord[j * 3 + 0];
        const float vy = ayp - scoord[j * 3 + 1];
        const float vz = azp - scoord[j * 3 + 2];
        const float d = sqrtf(vx * vx + vy * vy + vz * vz);
        const int sp = ssp[j];
        if (d <= F_RCR) {
            const float fc = 0.5f * __cosf(d * (F_PI / F_RCR)) + 0.5f;
            float* radbase = &rad[sp * 16];
#pragma unroll
            for (int k = 0; k < 16; ++k) {
                const float sh = 0.9f + 0.26875f * (float)k;  // linspace(0.9,5.2,17)[:-1]
                const float dd = d - sh;
                const float term = 0.25f * __expf(-16.0f * dd * dd) * fc;
                atomicAdd(&radbase[k], term);
            }
        }
        if (d <= F_RCA) {
            const int idx = atomicAdd(&Mcnt, 1);
            cfx[idx] = vx;
            cfy[idx] = vy;
            cfz[idx] = vz;
            cfd[idx] = d;
            cfc[idx] = 0.5f * __cosf(d * (F_PI / F_RCA)) + 0.5f;
            cfs[idx] = sp;
        }
    }
    __syncthreads();

    const int M = Mcnt;
    const int npairs = (M * (M - 1)) >> 1;

    // cos/sin of ShfZ[t] = (t+0.5)*pi/8
    const float cZ[8] = {0.98078528f, 0.83146961f, 0.55557023f, 0.19509032f,
                         -0.19509032f, -0.55557023f, -0.83146961f, -0.98078528f};
    const float sZ[8] = {0.19509032f, 0.55557023f, 0.83146961f, 0.98078528f,
                         0.98078528f, 0.83146961f, 0.55557023f, 0.19509032f};

    for (int p = tid; p < npairs; p += 128) {
        // decode upper-triangular pair index p -> (i, j), i < j < M
        // rowStart(i) = i*(2M - i - 1)/2
        int i = (int)((float)(2 * M - 1) * 0.5f -
                      0.5f * sqrtf((float)((2 * M - 1) * (2 * M - 1)) - 8.0f * (float)p));
        if (i < 0) i = 0;
        if (i > M - 2) i = M - 2;
        while (i > 0 && p < (i * (2 * M - i - 1)) / 2) --i;
        while (p >= ((i + 1) * (2 * M - i - 2)) / 2) ++i;
        const int j = i + 1 + (p - (i * (2 * M - i - 1)) / 2);

        const float d1 = cfd[i], d2 = cfd[j];
        const float dot = cfx[i] * cfx[j] + cfy[i] * cfy[j] + cfz[i] * cfz[j];
        const float cosang = 0.95f * dot / (d1 * d2);
        const float sinang = sqrtf(1.0f - cosang * cosang);  // |cosang| <= 0.95
        const float fcj = cfc[i] * cfc[j];
        const float dm = 0.5f * (d1 + d2);

        float f2[4];
#pragma unroll
        for (int k = 0; k < 4; ++k) {
            const float sh = 0.9f + 0.65f * (float)k;  // linspace(0.9,3.5,5)[:-1]
            const float dd = dm - sh;
            f2[k] = __expf(-8.0f * dd * dd);
        }

        int s1 = cfs[i], s2 = cfs[j];
        if (s1 > s2) { const int t = s1; s1 = s2; s2 = t; }
        const int q = s1 * 4 - (s1 * (s1 - 1)) / 2 + (s2 - s1);  // comb_with_repl index
        float* angbase = &ang[q * 32];

#pragma unroll
        for (int t = 0; t < 8; ++t) {
            // cos(arccos(cosang) - ShfZ[t]) = cosang*cZ + sinang*sZ
            const float b = 0.5f * (1.0f + cosang * cZ[t] + sinang * sZ[t]);
            const float b2 = b * b;
            const float b4 = b2 * b2;
            const float b8 = b4 * b4;
            const float b16 = b8 * b8;
            const float b32 = b16 * b16;  // (.)^Zeta, Zeta=32
            const float pre = 2.0f * b32 * fcj;
#pragma unroll
            for (int k = 0; k < 4; ++k) {
                atomicAdd(&angbase[k * 8 + t], pre * f2[k]);
            }
        }
    }
    __syncthreads();

    // vectorized output write: 384 floats = 96 float4 (row base 1536B-aligned)
    float4* orow4 = (float4*)(out + (size_t)(c * NA + a) * 384);
    if (tid < 96) {
        float4 v;
        const int base = tid * 4;
        if (base < 64) {
            v.x = rad[base + 0]; v.y = rad[base + 1];
            v.z = rad[base + 2]; v.w = rad[base + 3];
        } else {
            const int b = base - 64;
            v.x = ang[b + 0]; v.y = ang[b + 1];
            v.z = ang[b + 2]; v.w = ang[b + 3];
        }
        orow4[tid] = v;
    }
}

extern "C" void kernel_launch(void* const* d_in, const int* in_sizes, int n_in,
                              void* d_out, int out_size, void* d_ws, size_t ws_size,
                              hipStream_t stream) {
    const int* species = (const int*)d_in[0];
    const float* coords = (const float*)d_in[1];
    float* out = (float*)d_out;
    const int CA = in_sizes[0];  // C * 96
    aev_kernel<<<CA, 128, 0, stream>>>(species, coords, out);
}

// Round 4
// 16.998 us; speedup vs baseline: 1.0266x; 1.0031x over previous
//
#include <hip/hip_runtime.h>
#include <math.h>

#define NA 96
#define NN 95
#define F_RCR 5.2f
#define F_RCA 3.5f
#define F_PI 3.14159265358979323846f

// per-atom output layout: [0..63] radial (species*16 + shfR),
// [64..383] angular (qpair*32 + shfA*8 + shfZ)

__global__ __launch_bounds__(64) void aev_kernel(const int* __restrict__ species,
                                                 const float* __restrict__ coords,
                                                 float* __restrict__ out) {
    const int blk = blockIdx.x;
    const int c = blk / NA;
    const int a = blk % NA;
    const int tid = threadIdx.x;

    __shared__ float scoord[NA * 3];  // packed xyz
    __shared__ int ssp[NA];
    // compacted radial neighbor list (d <= RCR)
    __shared__ float rfd[NN], rfc[NN];
    __shared__ int rfs[NN];
    // compacted angular neighbor list (d <= RCA)
    __shared__ float cfx[NN], cfy[NN], cfz[NN], cfd[NN], cfc[NN];
    __shared__ int cfs[NN];
    __shared__ int Mcnt[2];  // [0]=angular count, [1]=radial count
    __shared__ float ang[320];

    // stage conformer data: 288 floats = 72 float4 (base c*1152 B, 16B-aligned)
    {
        const float4* src = (const float4*)(coords + (size_t)c * NA * 3);
        float4* dst = (float4*)scoord;
        for (int i = tid; i < 72; i += 64) dst[i] = src[i];
    }
    for (int i = tid; i < NA; i += 64) ssp[i] = species[c * NA + i];
    for (int i = tid; i < 320; i += 64) ang[i] = 0.0f;
    if (tid < 2) Mcnt[tid] = 0;
    __syncthreads();

    const float axp = scoord[a * 3 + 0], ayp = scoord[a * 3 + 1], azp = scoord[a * 3 + 2];

    // phase 1: neighbor distances + compaction (radial and angular lists)
    for (int n = tid; n < NN; n += 64) {
        int j = a + 1 + n;
        if (j >= NA) j -= NA;
        const float vx = axp - scoord[j * 3 + 0];
        const float vy = ayp - scoord[j * 3 + 1];
        const float vz = azp - scoord[j * 3 + 2];
        const float d = sqrtf(vx * vx + vy * vy + vz * vz);
        const int sp = ssp[j];
        if (d <= F_RCR) {
            const int idx = atomicAdd(&Mcnt[1], 1);
            rfd[idx] = d;
            rfc[idx] = 0.5f * __cosf(d * (F_PI / F_RCR)) + 0.5f;
            rfs[idx] = sp;
        }
        if (d <= F_RCA) {
            const int idx = atomicAdd(&Mcnt[0], 1);
            cfx[idx] = vx;
            cfy[idx] = vy;
            cfz[idx] = vz;
            cfd[idx] = d;
            cfc[idx] = 0.5f * __cosf(d * (F_PI / F_RCA)) + 0.5f;
            cfs[idx] = sp;
        }
    }
    __syncthreads();

    // phase 2a: radial, bin-owned — lane tid owns bin (sp = tid>>4, k = tid&15).
    // Broadcast LDS reads (same address across lanes = conflict-free).
    const int Mr = Mcnt[1];
    const int mysp = tid >> 4;
    const float mysh = 0.9f + 0.26875f * (float)(tid & 15);  // linspace(0.9,5.2,17)[:-1]
    float racc = 0.0f;
    for (int m = 0; m < Mr; ++m) {
        const float dd = rfd[m] - mysh;
        const float val = 0.25f * __expf(-16.0f * dd * dd) * rfc[m];
        racc += (rfs[m] == mysp) ? val : 0.0f;
    }

    // phase 2b: angular pairs with LDS atomics
    const int M = Mcnt[0];
    const int npairs = (M * (M - 1)) >> 1;

    // cos/sin of ShfZ[t] = (t+0.5)*pi/8
    const float cZ[8] = {0.98078528f, 0.83146961f, 0.55557023f, 0.19509032f,
                         -0.19509032f, -0.55557023f, -0.83146961f, -0.98078528f};
    const float sZ[8] = {0.19509032f, 0.55557023f, 0.83146961f, 0.98078528f,
                         0.98078528f, 0.83146961f, 0.55557023f, 0.19509032f};

    for (int p = tid; p < npairs; p += 64) {
        // decode upper-triangular pair index p -> (i, j), i < j < M
        int i = (int)((float)(2 * M - 1) * 0.5f -
                      0.5f * sqrtf((float)((2 * M - 1) * (2 * M - 1)) - 8.0f * (float)p));
        if (i < 0) i = 0;
        if (i > M - 2) i = M - 2;
        while (i > 0 && p < (i * (2 * M - i - 1)) / 2) --i;
        while (p >= ((i + 1) * (2 * M - i - 2)) / 2) ++i;
        const int j = i + 1 + (p - (i * (2 * M - i - 1)) / 2);

        const float d1 = cfd[i], d2 = cfd[j];
        const float dot = cfx[i] * cfx[j] + cfy[i] * cfy[j] + cfz[i] * cfz[j];
        const float cosang = 0.95f * dot / (d1 * d2);
        const float sinang = sqrtf(1.0f - cosang * cosang);  // |cosang| <= 0.95
        const float fcj = cfc[i] * cfc[j];
        const float dm = 0.5f * (d1 + d2);

        float f2[4];
#pragma unroll
        for (int k = 0; k < 4; ++k) {
            const float sh = 0.9f + 0.65f * (float)k;  // linspace(0.9,3.5,5)[:-1]
            const float dd = dm - sh;
            f2[k] = __expf(-8.0f * dd * dd);
        }

        int s1 = cfs[i], s2 = cfs[j];
        if (s1 > s2) { const int t = s1; s1 = s2; s2 = t; }
        const int q = s1 * 4 - (s1 * (s1 - 1)) / 2 + (s2 - s1);  // comb_with_repl index
        float* angbase = &ang[q * 32];

#pragma unroll
        for (int t = 0; t < 8; ++t) {
            // cos(arccos(cosang) - ShfZ[t]) = cosang*cZ + sinang*sZ
            const float b = 0.5f * (1.0f + cosang * cZ[t] + sinang * sZ[t]);
            const float b2 = b * b;
            const float b4 = b2 * b2;
            const float b8 = b4 * b4;
            const float b16 = b8 * b8;
            const float b32 = b16 * b16;  // (.)^Zeta, Zeta=32
            const float pre = 2.0f * b32 * fcj;
#pragma unroll
            for (int k = 0; k < 4; ++k) {
                atomicAdd(&angbase[k * 8 + t], pre * f2[k]);
            }
        }
    }
    __syncthreads();

    // output: radial straight from register, angular vectorized (80 float4)
    float* orow = out + (size_t)(c * NA + a) * 384;
    orow[tid] = racc;
    float4* oang4 = (float4*)(orow + 64);  // 16B-aligned (row base 1536B + 256B)
    const float4* ang4 = (const float4*)ang;
    for (int i = tid; i < 80; i += 64) oang4[i] = ang4[i];
}

extern "C" void kernel_launch(void* const* d_in, const int* in_sizes, int n_in,
                              void* d_out, int out_size, void* d_ws, size_t ws_size,
                              hipStream_t stream) {
    const int* species = (const int*)d_in[0];
    const float* coords = (const float*)d_in[1];
    float* out = (float*)d_out;
    const int CA = in_sizes[0];  // C * 96
    aev_kernel<<<CA, 64, 0, stream>>>(species, coords, out);
}